// Round 1
// baseline (1207.754 us; speedup 1.0000x reference)
//
#include <hip/hip_runtime.h>

#define NB_B 2
#define NB_S 2048
#define NB_D 1024
#define NB_H 16
#define NB_HD 64
#define NB_ROT 32

// ---------------- RoPE sin/cos table: S x 16 pairs x {sin,cos} ----------------
__global__ void k_rope_table(float* __restrict__ tab) {
  int i = blockIdx.x * blockDim.x + threadIdx.x;
  const int NP = NB_S * (NB_ROT / 2);  // 32768
  if (i >= NP) return;
  int s = i >> 4;
  int p = i & 15;
  float inv = powf(10000.0f, -(2.0f * (float)p) / (float)NB_ROT);
  float a = (float)s * inv;
  tab[2 * i + 0] = sinf(a);
  tab[2 * i + 1] = cosf(a);
}

// ---------------- fp32 GEMM  C = A @ W^T, 128x128x16 tile ----------------
// mode 0: Q (rope, BHSD out)  mode 1: K (rope, BHSD out)
// mode 2: V (BHSD out)        mode 3: plain row-major out
__global__ __launch_bounds__(256) void k_gemm(
    const float* __restrict__ A,
    const float* __restrict__ W0, const float* __restrict__ W1,
    const float* __restrict__ W2,
    float* __restrict__ O0, float* __restrict__ O1, float* __restrict__ O2,
    const float* __restrict__ tab, int mode_base) {
  const int z = blockIdx.z;
  const int mode = mode_base + z;
  const float* W = (z == 0) ? W0 : (z == 1) ? W1 : W2;
  float* O = (z == 0) ? O0 : (z == 1) ? O1 : O2;

  __shared__ float As[16][132];
  __shared__ float Bs[16][132];

  const int tid = threadIdx.x;
  const int m0 = blockIdx.y * 128;
  const int n0 = blockIdx.x * 128;
  const int tm4 = (tid >> 4) * 4;   // 0..60
  const int tn4 = (tid & 15) * 4;   // 0..60
  const int lr = tid >> 2;          // 0..63
  const int lk = (tid & 3) * 4;     // 0,4,8,12

  float acc[8][8];
#pragma unroll
  for (int i = 0; i < 8; ++i)
#pragma unroll
    for (int j = 0; j < 8; ++j) acc[i][j] = 0.0f;

  const float* pa0 = A + (size_t)(m0 + lr) * NB_D + lk;
  const float* pa1 = pa0 + (size_t)64 * NB_D;
  const float* pb0 = W + (size_t)(n0 + lr) * NB_D + lk;
  const float* pb1 = pb0 + (size_t)64 * NB_D;

  for (int k0 = 0; k0 < NB_D; k0 += 16) {
    float4 a0 = *(const float4*)(pa0 + k0);
    float4 a1 = *(const float4*)(pa1 + k0);
    float4 b0 = *(const float4*)(pb0 + k0);
    float4 b1 = *(const float4*)(pb1 + k0);
    __syncthreads();
    As[lk + 0][lr] = a0.x; As[lk + 1][lr] = a0.y; As[lk + 2][lr] = a0.z; As[lk + 3][lr] = a0.w;
    As[lk + 0][lr + 64] = a1.x; As[lk + 1][lr + 64] = a1.y; As[lk + 2][lr + 64] = a1.z; As[lk + 3][lr + 64] = a1.w;
    Bs[lk + 0][lr] = b0.x; Bs[lk + 1][lr] = b0.y; Bs[lk + 2][lr] = b0.z; Bs[lk + 3][lr] = b0.w;
    Bs[lk + 0][lr + 64] = b1.x; Bs[lk + 1][lr + 64] = b1.y; Bs[lk + 2][lr + 64] = b1.z; Bs[lk + 3][lr + 64] = b1.w;
    __syncthreads();
#pragma unroll
    for (int kk = 0; kk < 16; ++kk) {
      const float4 aA = *(const float4*)&As[kk][tm4];
      const float4 aB = *(const float4*)&As[kk][tm4 + 64];
      const float4 bA = *(const float4*)&Bs[kk][tn4];
      const float4 bB = *(const float4*)&Bs[kk][tn4 + 64];
      const float am[8] = {aA.x, aA.y, aA.z, aA.w, aB.x, aB.y, aB.z, aB.w};
      const float bn[8] = {bA.x, bA.y, bA.z, bA.w, bB.x, bB.y, bB.z, bB.w};
#pragma unroll
      for (int i = 0; i < 8; ++i)
#pragma unroll
        for (int j = 0; j < 8; ++j) acc[i][j] = fmaf(am[i], bn[j], acc[i][j]);
    }
  }

#pragma unroll
  for (int i = 0; i < 8; ++i) {
    const int lm = (i < 4) ? (tm4 + i) : (64 + tm4 + i - 4);
    const int gm = m0 + lm;
    if (mode == 3) {
      float* dst = O + (size_t)gm * NB_D;
      float4 c0 = {acc[i][0], acc[i][1], acc[i][2], acc[i][3]};
      float4 c1 = {acc[i][4], acc[i][5], acc[i][6], acc[i][7]};
      *(float4*)(dst + n0 + tn4) = c0;
      *(float4*)(dst + n0 + 64 + tn4) = c1;
    } else {
      const int b = gm >> 11;
      const int s = gm & (NB_S - 1);
#pragma unroll
      for (int h2 = 0; h2 < 2; ++h2) {
        const int gn = n0 + h2 * 64 + tn4;
        float v0 = acc[i][4 * h2 + 0], v1 = acc[i][4 * h2 + 1];
        float v2 = acc[i][4 * h2 + 2], v3 = acc[i][4 * h2 + 3];
        const int hh = gn >> 6;
        const int d0 = gn & 63;
        if (mode <= 1 && d0 < NB_ROT) {
          const int p0 = d0 >> 1;  // global pair index of v0/v1
          const float sn0 = tab[(s * 16 + p0) * 2 + 0];
          const float cs0 = tab[(s * 16 + p0) * 2 + 1];
          const float sn1 = tab[(s * 16 + p0 + 1) * 2 + 0];
          const float cs1 = tab[(s * 16 + p0 + 1) * 2 + 1];
          const float t0 = v0 * cs0 - v1 * sn0;
          const float t1 = v1 * cs0 + v0 * sn0;
          const float t2 = v2 * cs1 - v3 * sn1;
          const float t3 = v3 * cs1 + v2 * sn1;
          v0 = t0; v1 = t1; v2 = t2; v3 = t3;
        }
        float4 c = {v0, v1, v2, v3};
        float* dst = O + (((size_t)(b * NB_H + hh) * NB_S + s) * NB_HD + d0);
        *(float4*)dst = c;
      }
    }
  }
}

// ---------------- fp32 causal flash attention ----------------
// grid: (S/64 q-tiles, B*H). 256 threads: 4 threads per q-row.
__global__ __launch_bounds__(256) void k_attn(
    const float* __restrict__ Q, const float* __restrict__ K,
    const float* __restrict__ V, float* __restrict__ OA) {
  __shared__ float Ks[64][72];  // pad 72: k=qd+4j rows land on disjoint bank groups
  __shared__ float Vs[64][72];
  __shared__ float Ps[64][65];

  const int tid = threadIdx.x;
  const int r = tid >> 2;   // q-row within tile
  const int qd = tid & 3;   // quarter
  const int qt = blockIdx.x;
  const int bh = blockIdx.y;
  const int q0 = qt * 64;
  const int qg = q0 + r;

  const float* Qb = Q + (size_t)bh * NB_S * NB_HD;
  const float* Kb = K + (size_t)bh * NB_S * NB_HD;
  const float* Vb = V + (size_t)bh * NB_S * NB_HD;

  float4 qv[16];
#pragma unroll
  for (int j = 0; j < 16; ++j)
    qv[j] = *(const float4*)(Qb + (size_t)qg * 64 + 4 * j);

  float m = -INFINITY;
  float l = 0.0f;
  float o[16];
#pragma unroll
  for (int d = 0; d < 16; ++d) o[d] = 0.0f;

  for (int t = 0; t <= qt; ++t) {
    const int k0 = t * 64;
#pragma unroll
    for (int c = 0; c < 4; ++c) {
      const int col = qd * 4 + 16 * c;
      float4 kk4 = *(const float4*)(Kb + (size_t)(k0 + r) * 64 + col);
      float4 vv4 = *(const float4*)(Vb + (size_t)(k0 + r) * 64 + col);
      *(float4*)&Ks[r][col] = kk4;
      *(float4*)&Vs[r][col] = vv4;
    }
    __syncthreads();

    float sc[16];
#pragma unroll
    for (int j = 0; j < 16; ++j) {
      const int k = qd + 4 * j;  // strided -> conflict-free with pad 72
      float dot = 0.0f;
#pragma unroll
      for (int dj = 0; dj < 16; ++dj) {
        const float4 x = *(const float4*)&Ks[k][4 * dj];
        dot = fmaf(qv[dj].x, x.x, dot);
        dot = fmaf(qv[dj].y, x.y, dot);
        dot = fmaf(qv[dj].z, x.z, dot);
        dot = fmaf(qv[dj].w, x.w, dot);
      }
      const int kg = k0 + k;
      sc[j] = (kg <= qg) ? dot * 0.125f : -INFINITY;
    }

    float mloc = sc[0];
#pragma unroll
    for (int j = 1; j < 16; ++j) mloc = fmaxf(mloc, sc[j]);
    mloc = fmaxf(mloc, __shfl_xor(mloc, 1));
    mloc = fmaxf(mloc, __shfl_xor(mloc, 2));
    const float mnew = fmaxf(m, mloc);
    const float alpha = __expf(m - mnew);
    float psum = 0.0f;
#pragma unroll
    for (int j = 0; j < 16; ++j) {
      const float p = __expf(sc[j] - mnew);
      sc[j] = p;
      psum += p;
    }
    psum += __shfl_xor(psum, 1);
    psum += __shfl_xor(psum, 2);
    l = l * alpha + psum;
    m = mnew;
#pragma unroll
    for (int d = 0; d < 16; ++d) o[d] *= alpha;
#pragma unroll
    for (int j = 0; j < 16; ++j) Ps[r][qd + 4 * j] = sc[j];
    __syncthreads();

#pragma unroll 4
    for (int k = 0; k < 64; ++k) {
      const float p = Ps[r][k];
#pragma unroll
      for (int jj = 0; jj < 4; ++jj) {
        const float4 v4 = *(const float4*)&Vs[k][qd * 16 + 4 * jj];
        o[4 * jj + 0] = fmaf(p, v4.x, o[4 * jj + 0]);
        o[4 * jj + 1] = fmaf(p, v4.y, o[4 * jj + 1]);
        o[4 * jj + 2] = fmaf(p, v4.z, o[4 * jj + 2]);
        o[4 * jj + 3] = fmaf(p, v4.w, o[4 * jj + 3]);
      }
    }
    __syncthreads();
  }

  const float inv = 1.0f / l;
  const int b = bh >> 4;
  const int h = bh & 15;
  float* dst = OA + (((size_t)b * NB_S + qg) * NB_H + h) * NB_HD + qd * 16;
#pragma unroll
  for (int jj = 0; jj < 4; ++jj) {
    float4 c = {o[4 * jj + 0] * inv, o[4 * jj + 1] * inv,
                o[4 * jj + 2] * inv, o[4 * jj + 3] * inv};
    *(float4*)(dst + 4 * jj) = c;
  }
}

extern "C" void kernel_launch(void* const* d_in, const int* in_sizes, int n_in,
                              void* d_out, int out_size, void* d_ws, size_t ws_size,
                              hipStream_t stream) {
  const float* hs = (const float*)d_in[0];
  const float* wq = (const float*)d_in[1];
  const float* wk = (const float*)d_in[2];
  const float* wv = (const float*)d_in[3];
  const float* wo = (const float*)d_in[4];
  float* out = (float*)d_out;
  float* ws = (float*)d_ws;

  const size_t E = (size_t)NB_B * NB_S * NB_D;  // 4194304
  float* Qd = ws;
  float* Kd = ws + E;
  float* Vd = ws + 2 * E;
  float* attn = ws + 3 * E;
  float* tab = ws + 4 * E;  // 65536 floats

  k_rope_table<<<dim3(128), 256, 0, stream>>>(tab);
  k_gemm<<<dim3(8, 32, 3), 256, 0, stream>>>(hs, wq, wk, wv, Qd, Kd, Vd, tab, 0);
  k_attn<<<dim3(32, 32), 256, 0, stream>>>(Qd, Kd, Vd, attn);
  k_gemm<<<dim3(8, 32, 1), 256, 0, stream>>>(attn, wo, wo, wo, out, out, out, tab, 3);
}

// Round 2
// 780.067 us; speedup vs baseline: 1.5483x; 1.5483x over previous
//
#include <hip/hip_runtime.h>

#define NB_B 2
#define NB_S 2048
#define NB_D 1024
#define NB_H 16
#define NB_HD 64
#define NB_ROT 32

typedef __bf16 bf16x8 __attribute__((ext_vector_type(8)));
typedef float f32x4 __attribute__((ext_vector_type(4)));

__device__ inline f32x4 mfma16(bf16x8 a, bf16x8 b, f32x4 c) {
  return __builtin_amdgcn_mfma_f32_16x16x32_bf16(a, b, c, 0, 0, 0);
}

// float -> bf16 bits, round-to-nearest-even (finite inputs)
__device__ inline unsigned short f2bf(float f) {
  unsigned u = __builtin_bit_cast(unsigned, f);
  unsigned r = (u + 0x7fffu + ((u >> 16) & 1u)) >> 16;
  return (unsigned short)r;
}

// ---------------- RoPE sin/cos table: S x 16 pairs x {sin,cos} ----------------
__global__ void k_rope_table(float* __restrict__ tab) {
  int i = blockIdx.x * blockDim.x + threadIdx.x;
  const int NP = NB_S * (NB_ROT / 2);
  if (i >= NP) return;
  int s = i >> 4;
  int p = i & 15;
  float inv = powf(10000.0f, -(2.0f * (float)p) / (float)NB_ROT);
  float a = (float)s * inv;
  tab[2 * i + 0] = sinf(a);
  tab[2 * i + 1] = cosf(a);
}

// ---------------- fp32 GEMM  C = A @ W^T, 128x128x16 tile ----------------
// mode 0: Q rope -> bf16 (bh,s,hd)   mode 1: K rope -> bf16 (bh,s,hd)
// mode 2: V -> bf16 TRANSPOSED (bh,hd,s)   mode 3: fp32 row-major out
__global__ __launch_bounds__(256) void k_gemm(
    const float* __restrict__ A,
    const float* __restrict__ W0, const float* __restrict__ W1,
    const float* __restrict__ W2,
    float* __restrict__ O0, float* __restrict__ O1, float* __restrict__ O2,
    const float* __restrict__ tab, int mode_base) {
  const int z = blockIdx.z;
  const int mode = mode_base + z;
  const float* W = (z == 0) ? W0 : (z == 1) ? W1 : W2;
  float* O = (z == 0) ? O0 : (z == 1) ? O1 : O2;

  __shared__ float As[16][132];
  __shared__ float Bs[16][132];

  const int tid = threadIdx.x;
  const int m0 = blockIdx.y * 128;
  const int n0 = blockIdx.x * 128;
  const int tm4 = (tid >> 4) * 4;
  const int tn4 = (tid & 15) * 4;
  const int lr = tid >> 2;
  const int lk = (tid & 3) * 4;

  float acc[8][8];
#pragma unroll
  for (int i = 0; i < 8; ++i)
#pragma unroll
    for (int j = 0; j < 8; ++j) acc[i][j] = 0.0f;

  const float* pa0 = A + (size_t)(m0 + lr) * NB_D + lk;
  const float* pa1 = pa0 + (size_t)64 * NB_D;
  const float* pb0 = W + (size_t)(n0 + lr) * NB_D + lk;
  const float* pb1 = pb0 + (size_t)64 * NB_D;

  for (int k0 = 0; k0 < NB_D; k0 += 16) {
    float4 a0 = *(const float4*)(pa0 + k0);
    float4 a1 = *(const float4*)(pa1 + k0);
    float4 b0 = *(const float4*)(pb0 + k0);
    float4 b1 = *(const float4*)(pb1 + k0);
    __syncthreads();
    As[lk + 0][lr] = a0.x; As[lk + 1][lr] = a0.y; As[lk + 2][lr] = a0.z; As[lk + 3][lr] = a0.w;
    As[lk + 0][lr + 64] = a1.x; As[lk + 1][lr + 64] = a1.y; As[lk + 2][lr + 64] = a1.z; As[lk + 3][lr + 64] = a1.w;
    Bs[lk + 0][lr] = b0.x; Bs[lk + 1][lr] = b0.y; Bs[lk + 2][lr] = b0.z; Bs[lk + 3][lr] = b0.w;
    Bs[lk + 0][lr + 64] = b1.x; Bs[lk + 1][lr + 64] = b1.y; Bs[lk + 2][lr + 64] = b1.z; Bs[lk + 3][lr + 64] = b1.w;
    __syncthreads();
#pragma unroll
    for (int kk = 0; kk < 16; ++kk) {
      const float4 aA = *(const float4*)&As[kk][tm4];
      const float4 aB = *(const float4*)&As[kk][tm4 + 64];
      const float4 bA = *(const float4*)&Bs[kk][tn4];
      const float4 bB = *(const float4*)&Bs[kk][tn4 + 64];
      const float am[8] = {aA.x, aA.y, aA.z, aA.w, aB.x, aB.y, aB.z, aB.w};
      const float bn[8] = {bA.x, bA.y, bA.z, bA.w, bB.x, bB.y, bB.z, bB.w};
#pragma unroll
      for (int i = 0; i < 8; ++i)
#pragma unroll
        for (int j = 0; j < 8; ++j) acc[i][j] = fmaf(am[i], bn[j], acc[i][j]);
    }
  }

  if (mode == 3) {
#pragma unroll
    for (int i = 0; i < 8; ++i) {
      const int lm = (i < 4) ? (tm4 + i) : (64 + tm4 + i - 4);
      const int gm = m0 + lm;
      float* dst = O + (size_t)gm * NB_D;
      float4 c0 = {acc[i][0], acc[i][1], acc[i][2], acc[i][3]};
      float4 c1 = {acc[i][4], acc[i][5], acc[i][6], acc[i][7]};
      *(float4*)(dst + n0 + tn4) = c0;
      *(float4*)(dst + n0 + 64 + tn4) = c1;
    }
  } else if (mode == 2) {
    // V transposed: Vt[(b*16+hh)*64 + d0][s], bf16
    ushort* Ov = (ushort*)O;
#pragma unroll
    for (int ib = 0; ib < 2; ++ib) {
      const int gm0 = m0 + ib * 64 + tm4;  // 4 consecutive s-rows
      const int b = gm0 >> 11;
      const int s0 = gm0 & (NB_S - 1);
#pragma unroll
      for (int h2 = 0; h2 < 2; ++h2)
#pragma unroll
        for (int jj = 0; jj < 4; ++jj) {
          const int gn = n0 + h2 * 64 + tn4 + jj;
          const int hh = gn >> 6;
          const int d0 = gn & 63;
          ushort4 pk;
          pk.x = f2bf(acc[ib * 4 + 0][h2 * 4 + jj]);
          pk.y = f2bf(acc[ib * 4 + 1][h2 * 4 + jj]);
          pk.z = f2bf(acc[ib * 4 + 2][h2 * 4 + jj]);
          pk.w = f2bf(acc[ib * 4 + 3][h2 * 4 + jj]);
          *(ushort4*)(Ov + ((size_t)((b * NB_H + hh) * NB_HD + d0)) * NB_S + s0) = pk;
        }
    }
  } else {
    // Q/K with rope -> bf16 (bh, s, hd)
    ushort* Oq = (ushort*)O;
#pragma unroll
    for (int i = 0; i < 8; ++i) {
      const int lm = (i < 4) ? (tm4 + i) : (64 + tm4 + i - 4);
      const int gm = m0 + lm;
      const int b = gm >> 11;
      const int s = gm & (NB_S - 1);
#pragma unroll
      for (int h2 = 0; h2 < 2; ++h2) {
        const int gn = n0 + h2 * 64 + tn4;
        float v0 = acc[i][4 * h2 + 0], v1 = acc[i][4 * h2 + 1];
        float v2 = acc[i][4 * h2 + 2], v3 = acc[i][4 * h2 + 3];
        const int hh = gn >> 6;
        const int d0 = gn & 63;
        if (d0 < NB_ROT) {
          const int p0 = d0 >> 1;
          const float sn0 = tab[(s * 16 + p0) * 2 + 0];
          const float cs0 = tab[(s * 16 + p0) * 2 + 1];
          const float sn1 = tab[(s * 16 + p0 + 1) * 2 + 0];
          const float cs1 = tab[(s * 16 + p0 + 1) * 2 + 1];
          const float t0 = v0 * cs0 - v1 * sn0;
          const float t1 = v1 * cs0 + v0 * sn0;
          const float t2 = v2 * cs1 - v3 * sn1;
          const float t3 = v3 * cs1 + v2 * sn1;
          v0 = t0; v1 = t1; v2 = t2; v3 = t3;
        }
        ushort4 pk = {f2bf(v0), f2bf(v1), f2bf(v2), f2bf(v3)};
        *(ushort4*)(Oq + (((size_t)(b * NB_H + hh) * NB_S + s) * NB_HD + d0)) = pk;
      }
    }
  }
}

// ---------------- bf16 MFMA causal flash attention ----------------
// grid (32 qtiles, 32 bh), 256 thr = 4 waves; wave owns 16 q-rows.
// Q,K bf16 (bh,s,64); Vt bf16 (bh,64,S). Output fp32 (b,s,h,hd).
__global__ __launch_bounds__(256) void k_attn(
    const ushort* __restrict__ Q, const ushort* __restrict__ K,
    const ushort* __restrict__ Vt, float* __restrict__ OA) {
  __shared__ __align__(16) unsigned char KsB[8192];   // [64 kk][64 hd] bf16, xor-swz
  __shared__ __align__(16) unsigned char VsB[8192];   // [64 hd][64 kk] bf16, xor-swz
  __shared__ __align__(16) unsigned char PsB[9216];   // per-wave [16 q][72 kk] bf16

  const int tid = threadIdx.x;
  const int wid = tid >> 6;
  const int lane = tid & 63;
  const int lq = lane & 15;
  const int g = lane >> 4;

  const int qt = 31 - blockIdx.x;  // heaviest tiles first
  const int bh = blockIdx.y;
  const int q0 = qt * 64;
  const int qg = q0 + wid * 16 + lq;

  const ushort* Kb = K + (size_t)bh * NB_S * NB_HD;
  const ushort* Vb = Vt + (size_t)bh * NB_HD * NB_S;

  // Q fragments (B-operand): lane holds Q[q=lq][hd=32s+8g+j]
  const ushort* Qrow = Q + ((size_t)bh * NB_S + qg) * NB_HD;
  const bf16x8 qf0 = *(const bf16x8*)(Qrow + 8 * g);
  const bf16x8 qf1 = *(const bf16x8*)(Qrow + 32 + 8 * g);

  float m = -INFINITY;
  float l = 0.0f;
  f32x4 o[4];
#pragma unroll
  for (int ht = 0; ht < 4; ++ht) o[ht] = (f32x4){0.f, 0.f, 0.f, 0.f};

  const int swz = (lq & 7) << 4;
  const unsigned char* Pw = PsB + wid * 2304;

  for (int t = 0; t <= qt; ++t) {
    const int k0 = t * 64;
    // ---- stage K tile [kk][hd] and Vt tile [hd][kk], both xor-swizzled ----
#pragma unroll
    for (int i = 0; i < 2; ++i) {
      const int ch = tid + 256 * i;       // 0..511
      const int row = ch >> 3;            // 0..63
      const int c16 = ch & 7;             // 16B chunk in row
      const int dst = ((row << 7) + (c16 << 4)) ^ ((row & 7) << 4);
      uint4 kd = *(const uint4*)(Kb + (size_t)(k0 + row) * NB_HD + c16 * 8);
      *(uint4*)(KsB + dst) = kd;
      uint4 vd = *(const uint4*)(Vb + (size_t)row * NB_S + k0 + c16 * 8);
      *(uint4*)(VsB + dst) = vd;
    }
    __syncthreads();

    // ---- scores S^T = K · Q^T : D[kk][q], wave's 16 q cols ----
    f32x4 sc[4];
#pragma unroll
    for (int c = 0; c < 4; ++c) {
      const int rb = (16 * c + lq) << 7;
      const bf16x8 a0 = *(const bf16x8*)(KsB + ((rb + (g << 4)) ^ swz));
      const bf16x8 a1 = *(const bf16x8*)(KsB + ((rb + 64 + (g << 4)) ^ swz));
      f32x4 z = {0.f, 0.f, 0.f, 0.f};
      z = mfma16(a0, qf0, z);
      z = mfma16(a1, qf1, z);
      sc[c] = z;
    }

    // ---- masked online softmax; lane owns q=lq (replicated over 4 groups) ----
    float vals[4][4];
#pragma unroll
    for (int c = 0; c < 4; ++c)
#pragma unroll
      for (int r = 0; r < 4; ++r) {
        const int kk = k0 + 16 * c + 4 * g + r;
        vals[c][r] = (kk <= qg) ? sc[c][r] * 0.125f : -INFINITY;
      }
    float pm = vals[0][0];
#pragma unroll
    for (int c = 0; c < 4; ++c)
#pragma unroll
      for (int r = 0; r < 4; ++r) pm = fmaxf(pm, vals[c][r]);
    pm = fmaxf(pm, __shfl_xor(pm, 16));
    pm = fmaxf(pm, __shfl_xor(pm, 32));
    const float mnew = fmaxf(m, pm);
    const float alpha = __expf(m - mnew);
    float psum = 0.0f;
#pragma unroll
    for (int c = 0; c < 4; ++c)
#pragma unroll
      for (int r = 0; r < 4; ++r) {
        const float p = __expf(vals[c][r] - mnew);
        vals[c][r] = p;
        psum += p;
      }
    psum += __shfl_xor(psum, 16);
    psum += __shfl_xor(psum, 32);
    l = l * alpha + psum;
    m = mnew;

    // ---- P -> LDS bf16 (per-wave region, row pad 72 elems) ----
#pragma unroll
    for (int c = 0; c < 4; ++c) {
      uint2 pk;
      pk.x = (unsigned)f2bf(vals[c][0]) | ((unsigned)f2bf(vals[c][1]) << 16);
      pk.y = (unsigned)f2bf(vals[c][2]) | ((unsigned)f2bf(vals[c][3]) << 16);
      *(uint2*)(Pw + lq * 144 + 32 * c + 8 * g) = pk;
    }

    // ---- rescale O rows (q = 4g+r needs alpha from lane lq==4g+r) ----
#pragma unroll
    for (int r = 0; r < 4; ++r) {
      const float ar = __shfl(alpha, 4 * g + r);
#pragma unroll
      for (int ht = 0; ht < 4; ++ht) o[ht][r] *= ar;
    }

    // ---- PV: O[q][hd] += P · V ----
#pragma unroll
    for (int ht = 0; ht < 4; ++ht) {
      const int vb = (16 * ht + lq) << 7;
#pragma unroll
      for (int s = 0; s < 2; ++s) {
        const bf16x8 pf = *(const bf16x8*)(Pw + lq * 144 + 64 * s + 16 * g);
        const bf16x8 vf = *(const bf16x8*)(VsB + ((vb + (s << 6) + (g << 4)) ^ swz));
        o[ht] = mfma16(pf, vf, o[ht]);
      }
    }
    __syncthreads();
  }

  // ---- epilogue: divide by l, store fp32 (b, s, h, hd) ----
  const int b = bh >> 4;
  const int h = bh & 15;
#pragma unroll
  for (int r = 0; r < 4; ++r) {
    const float linv = 1.0f / __shfl(l, 4 * g + r);
    const int srow = q0 + wid * 16 + 4 * g + r;
    float* dst = OA + (((size_t)b * NB_S + srow) * NB_H + h) * NB_HD;
#pragma unroll
    for (int ht = 0; ht < 4; ++ht) dst[16 * ht + lq] = o[ht][r] * linv;
  }
}

extern "C" void kernel_launch(void* const* d_in, const int* in_sizes, int n_in,
                              void* d_out, int out_size, void* d_ws, size_t ws_size,
                              hipStream_t stream) {
  const float* hs = (const float*)d_in[0];
  const float* wq = (const float*)d_in[1];
  const float* wk = (const float*)d_in[2];
  const float* wv = (const float*)d_in[3];
  const float* wo = (const float*)d_in[4];
  float* out = (float*)d_out;

  const size_t E = (size_t)NB_B * NB_S * NB_D;  // 4194304
  ushort* Qd = (ushort*)d_ws;
  ushort* Kd = Qd + E;
  ushort* Vt = Kd + E;                 // (bh, hd, S)
  float* attn = (float*)(Vt + E);      // fp32 (b,s,h,hd)
  float* tab = attn + E;

  k_rope_table<<<dim3(128), 256, 0, stream>>>(tab);
  k_gemm<<<dim3(8, 32, 3), 256, 0, stream>>>(hs, wq, wk, wv,
                                             (float*)Qd, (float*)Kd, (float*)Vt, tab, 0);
  k_attn<<<dim3(32, 32), 256, 0, stream>>>(Qd, Kd, Vt, attn);
  k_gemm<<<dim3(8, 32, 1), 256, 0, stream>>>(attn, wo, wo, wo, out, out, out, tab, 3);
}

// Round 3
// 358.521 us; speedup vs baseline: 3.3687x; 2.1758x over previous
//
#include <hip/hip_runtime.h>

#define NB_B 2
#define NB_S 2048
#define NB_D 1024
#define NB_H 16
#define NB_HD 64
#define NB_ROT 32

typedef __bf16 bf16x8 __attribute__((ext_vector_type(8)));
typedef float f32x4 __attribute__((ext_vector_type(4)));

__device__ inline f32x4 mfma16(bf16x8 a, bf16x8 b, f32x4 c) {
  return __builtin_amdgcn_mfma_f32_16x16x32_bf16(a, b, c, 0, 0, 0);
}

// float -> bf16 bits, round-to-nearest-even (finite inputs)
__device__ inline unsigned short f2bf(float f) {
  unsigned u = __builtin_bit_cast(unsigned, f);
  unsigned r = (u + 0x7fffu + ((u >> 16) & 1u)) >> 16;
  return (unsigned short)r;
}
__device__ inline float bf2f(unsigned short h) {
  return __builtin_bit_cast(float, (unsigned)h << 16);
}

// async global->LDS, 16 B per lane; lds dest = uniform base + lane*16
__device__ inline void async16(const void* g, void* l) {
  __builtin_amdgcn_global_load_lds((const __attribute__((address_space(1))) unsigned int*)g,
                                   (__attribute__((address_space(3))) unsigned int*)l, 16, 0, 0);
}

// ---------------- RoPE sin/cos table ----------------
__global__ void k_rope_table(float* __restrict__ tab) {
  int i = blockIdx.x * blockDim.x + threadIdx.x;
  const int NP = NB_S * (NB_ROT / 2);
  if (i >= NP) return;
  int s = i >> 4;
  int p = i & 15;
  float inv = powf(10000.0f, -(2.0f * (float)p) / (float)NB_ROT);
  float a = (float)s * inv;
  tab[2 * i + 0] = sinf(a);
  tab[2 * i + 1] = cosf(a);
}

// ---------------- fp32 -> bf16 hi/lo split (8 elems/thread) ----------------
__global__ __launch_bounds__(256) void k_split(const float* __restrict__ src,
                                               ushort* __restrict__ hi,
                                               ushort* __restrict__ lo) {
  const int i = (blockIdx.x * 256 + threadIdx.x) * 8;
  float4 a = *(const float4*)(src + i);
  float4 b = *(const float4*)(src + i + 4);
  float v[8] = {a.x, a.y, a.z, a.w, b.x, b.y, b.z, b.w};
  ushort h[8], l[8];
#pragma unroll
  for (int j = 0; j < 8; ++j) {
    h[j] = f2bf(v[j]);
    l[j] = f2bf(v[j] - bf2f(h[j]));
  }
  ushort4 h0 = {h[0], h[1], h[2], h[3]}, h1 = {h[4], h[5], h[6], h[7]};
  ushort4 l0 = {l[0], l[1], l[2], l[3]}, l1 = {l[4], l[5], l[6], l[7]};
  *(ushort4*)(hi + i) = h0; *(ushort4*)(hi + i + 4) = h1;
  *(ushort4*)(lo + i) = l0; *(ushort4*)(lo + i + 4) = l1;
}

// all 4 weight matrices in one launch (z selects)
__global__ __launch_bounds__(256) void k_splitw(
    const float* __restrict__ s0, const float* __restrict__ s1,
    const float* __restrict__ s2, const float* __restrict__ s3,
    ushort* __restrict__ hi, ushort* __restrict__ lo) {
  const int z = blockIdx.z;
  const float* src = (z == 0) ? s0 : (z == 1) ? s1 : (z == 2) ? s2 : s3;
  ushort* h = hi + ((size_t)z << 20);
  ushort* l = lo + ((size_t)z << 20);
  const int i = (blockIdx.x * 256 + threadIdx.x) * 8;
  float4 a = *(const float4*)(src + i);
  float4 b = *(const float4*)(src + i + 4);
  float v[8] = {a.x, a.y, a.z, a.w, b.x, b.y, b.z, b.w};
  ushort hh[8], ll[8];
#pragma unroll
  for (int j = 0; j < 8; ++j) {
    hh[j] = f2bf(v[j]);
    ll[j] = f2bf(v[j] - bf2f(hh[j]));
  }
  ushort4 h0 = {hh[0], hh[1], hh[2], hh[3]}, h1 = {hh[4], hh[5], hh[6], hh[7]};
  ushort4 l0 = {ll[0], ll[1], ll[2], ll[3]}, l1 = {ll[4], ll[5], ll[6], ll[7]};
  *(ushort4*)(h + i) = h0; *(ushort4*)(h + i + 4) = h1;
  *(ushort4*)(l + i) = l0; *(ushort4*)(l + i + 4) = l1;
}

// ---------------- split-bf16 MFMA GEMM  C = A @ W^T ----------------
// 128x128 tile, BK=32, 4 waves x (64x64). Fragment-order LDS (conflict-free).
// TR=0: D[m][n]  (V: mode 2 -> bf16 Vt (bh,hd,S);  wo: mode 3 -> fp32 row-major)
// TR=1: D[n][m]  (Q/K: rope lane-local -> bf16 (bh,s,hd))
template <int TR>
__global__ __launch_bounds__(256) void k_gemm_mfma(
    const ushort* __restrict__ Ahi, const ushort* __restrict__ Alo,
    const ushort* __restrict__ Whi, const ushort* __restrict__ Wlo,
    void* __restrict__ O0, void* __restrict__ O1,
    const float* __restrict__ tab, int mode_base) {
  __shared__ __align__(16) ushort AhS[4096];
  __shared__ __align__(16) ushort AlS[4096];
  __shared__ __align__(16) ushort WhS[4096];
  __shared__ __align__(16) ushort WlS[4096];

  const int tid = threadIdx.x;
  const int wid = tid >> 6;
  const int lane = tid & 63;
  const int lq = lane & 15;
  const int g = lane >> 4;

  const int z = blockIdx.z;
  const int mode = mode_base + z;
  const ushort* wh = Whi + ((size_t)z << 20);
  const ushort* wl = Wlo + ((size_t)z << 20);
  void* O = (z == 0) ? O0 : O1;

  const int m0 = blockIdx.y * 128;
  const int n0 = blockIdx.x * 128;

  // wave wid stages the whole region {0:Ah, 1:Al, 2:Wh, 3:Wl}
  const ushort* gsb;
  ushort* lsb;
  int rowb;
  if (wid == 0)      { gsb = Ahi; rowb = m0; lsb = AhS; }
  else if (wid == 1) { gsb = Alo; rowb = m0; lsb = AlS; }
  else if (wid == 2) { gsb = wh;  rowb = n0; lsb = WhS; }
  else               { gsb = wl;  rowb = n0; lsb = WlS; }
  const ushort* gp = gsb + (size_t)(rowb + lq) * NB_D + g * 8;

  f32x4 acc[4][4];
#pragma unroll
  for (int i = 0; i < 4; ++i)
#pragma unroll
    for (int j = 0; j < 4; ++j) acc[i][j] = (f32x4){0.f, 0.f, 0.f, 0.f};

  const int ma = (wid & 1) * 4;   // A mb base for this wave
  const int nb = (wid >> 1) * 4;  // W nb base

  for (int k0 = 0; k0 < NB_D; k0 += 32) {
#pragma unroll
    for (int j = 0; j < 8; ++j)
      async16((const void*)(gp + (size_t)j * 16 * NB_D + k0), (void*)(lsb + j * 512));
    __syncthreads();  // drains vmcnt(0) before barrier

    bf16x8 fah[4], fal[4], fwh[4], fwl[4];
#pragma unroll
    for (int i = 0; i < 4; ++i) {
      fah[i] = *(const bf16x8*)(AhS + (ma + i) * 512 + lane * 8);
      fal[i] = *(const bf16x8*)(AlS + (ma + i) * 512 + lane * 8);
      fwh[i] = *(const bf16x8*)(WhS + (nb + i) * 512 + lane * 8);
      fwl[i] = *(const bf16x8*)(WlS + (nb + i) * 512 + lane * 8);
    }
#pragma unroll
    for (int i = 0; i < 4; ++i)
#pragma unroll
      for (int j = 0; j < 4; ++j) {
        if (TR == 0) {
          f32x4 c = acc[i][j];
          c = mfma16(fah[i], fwh[j], c);
          c = mfma16(fah[i], fwl[j], c);
          c = mfma16(fal[i], fwh[j], c);
          acc[i][j] = c;
        } else {
          f32x4 c = acc[j][i];
          c = mfma16(fwh[j], fah[i], c);
          c = mfma16(fwh[j], fal[i], c);
          c = mfma16(fwl[j], fah[i], c);
          acc[j][i] = c;
        }
      }
    __syncthreads();
  }

  const int wm = (wid & 1) * 64;
  const int wn = (wid >> 1) * 64;

  if (TR == 0) {
    if (mode == 3) {
      float* out = (float*)O;
#pragma unroll
      for (int i = 0; i < 4; ++i)
#pragma unroll
        for (int j = 0; j < 4; ++j) {
          const int col = n0 + wn + j * 16 + lq;
#pragma unroll
          for (int r = 0; r < 4; ++r) {
            const int row = m0 + wm + i * 16 + 4 * g + r;
            out[(size_t)row * NB_D + col] = acc[i][j][r];
          }
        }
    } else {  // V -> bf16 transposed (bh, hd, S)
      ushort* ov = (ushort*)O;
#pragma unroll
      for (int i = 0; i < 4; ++i) {
        const int gm0 = m0 + wm + i * 16 + 4 * g;
        const int b = gm0 >> 11;
        const int s0 = gm0 & (NB_S - 1);
#pragma unroll
        for (int j = 0; j < 4; ++j) {
          const int gn = n0 + wn + j * 16 + lq;
          const int hh = gn >> 6;
          const int d0 = gn & 63;
          ushort4 pk = {f2bf(acc[i][j][0]), f2bf(acc[i][j][1]),
                        f2bf(acc[i][j][2]), f2bf(acc[i][j][3])};
          *(ushort4*)(ov + ((size_t)((b * NB_H + hh) * NB_HD + d0)) * NB_S + s0) = pk;
        }
      }
    }
  } else {  // TR==1: Q/K, rope lane-local, bf16 (bh, s, hd)
    ushort* oq = (ushort*)O;
#pragma unroll
    for (int jn = 0; jn < 4; ++jn) {
      const int gn0 = n0 + wn + jn * 16 + 4 * g;  // 4 consecutive d-dims
      const int hh = gn0 >> 6;
      const int d0 = gn0 & 63;
#pragma unroll
      for (int im = 0; im < 4; ++im) {
        const int gm = m0 + wm + im * 16 + lq;
        const int b = gm >> 11;
        const int s = gm & (NB_S - 1);
        float v0 = acc[jn][im][0], v1 = acc[jn][im][1];
        float v2 = acc[jn][im][2], v3 = acc[jn][im][3];
        if (d0 < NB_ROT) {
          const int p0 = d0 >> 1;
          const float2 t0 = *(const float2*)(tab + ((s * 16 + p0) << 1));
          const float2 t1 = *(const float2*)(tab + ((s * 16 + p0 + 1) << 1));
          const float n0v = v0 * t0.y - v1 * t0.x;
          const float n1v = v1 * t0.y + v0 * t0.x;
          const float n2v = v2 * t1.y - v3 * t1.x;
          const float n3v = v3 * t1.y + v2 * t1.x;
          v0 = n0v; v1 = n1v; v2 = n2v; v3 = n3v;
        }
        ushort4 pk = {f2bf(v0), f2bf(v1), f2bf(v2), f2bf(v3)};
        *(ushort4*)(oq + ((size_t)(b * NB_H + hh) * NB_S + s) * NB_HD + d0) = pk;
      }
    }
  }
}

// ---------------- bf16 MFMA causal flash attention ----------------
// grid (32 qtiles, 32 bh), 256 thr = 4 waves; wave owns 16 q-rows.
// Q,K bf16 (bh,s,64); Vt bf16 (bh,64,S). Output split bf16 hi/lo (b,s,D).
__global__ __launch_bounds__(256) void k_attn(
    const ushort* __restrict__ Q, const ushort* __restrict__ K,
    const ushort* __restrict__ Vt, ushort* __restrict__ OH,
    ushort* __restrict__ OL) {
  __shared__ __align__(16) unsigned char KsB[8192];   // [64 kk][64 hd] bf16, xor-swz
  __shared__ __align__(16) unsigned char VsB[8192];   // [64 hd][64 kk] bf16, xor-swz
  __shared__ __align__(16) unsigned char PsB[9216];   // per-wave [16 q][72 kk] bf16

  const int tid = threadIdx.x;
  const int wid = tid >> 6;
  const int lane = tid & 63;
  const int lq = lane & 15;
  const int g = lane >> 4;

  const int qt = 31 - blockIdx.x;  // heaviest tiles first
  const int bh = blockIdx.y;
  const int q0 = qt * 64;
  const int qg = q0 + wid * 16 + lq;

  const ushort* Kb = K + (size_t)bh * NB_S * NB_HD;
  const ushort* Vb = Vt + (size_t)bh * NB_HD * NB_S;

  const ushort* Qrow = Q + ((size_t)bh * NB_S + qg) * NB_HD;
  const bf16x8 qf0 = *(const bf16x8*)(Qrow + 8 * g);
  const bf16x8 qf1 = *(const bf16x8*)(Qrow + 32 + 8 * g);

  float m = -INFINITY;
  float l = 0.0f;
  f32x4 o[4];
#pragma unroll
  for (int ht = 0; ht < 4; ++ht) o[ht] = (f32x4){0.f, 0.f, 0.f, 0.f};

  const int swz = (lq & 7) << 4;
  const unsigned char* Pw = PsB + wid * 2304;

  for (int t = 0; t <= qt; ++t) {
    const int k0 = t * 64;
#pragma unroll
    for (int i = 0; i < 2; ++i) {
      const int ch = tid + 256 * i;
      const int row = ch >> 3;
      const int c16 = ch & 7;
      const int dst = ((row << 7) + (c16 << 4)) ^ ((row & 7) << 4);
      uint4 kd = *(const uint4*)(Kb + (size_t)(k0 + row) * NB_HD + c16 * 8);
      *(uint4*)(KsB + dst) = kd;
      uint4 vd = *(const uint4*)(Vb + (size_t)row * NB_S + k0 + c16 * 8);
      *(uint4*)(VsB + dst) = vd;
    }
    __syncthreads();

    f32x4 sc[4];
#pragma unroll
    for (int c = 0; c < 4; ++c) {
      const int rb = (16 * c + lq) << 7;
      const bf16x8 a0 = *(const bf16x8*)(KsB + ((rb + (g << 4)) ^ swz));
      const bf16x8 a1 = *(const bf16x8*)(KsB + ((rb + 64 + (g << 4)) ^ swz));
      f32x4 zz = {0.f, 0.f, 0.f, 0.f};
      zz = mfma16(a0, qf0, zz);
      zz = mfma16(a1, qf1, zz);
      sc[c] = zz;
    }

    float vals[4][4];
#pragma unroll
    for (int c = 0; c < 4; ++c)
#pragma unroll
      for (int r = 0; r < 4; ++r) {
        const int kk = k0 + 16 * c + 4 * g + r;
        vals[c][r] = (kk <= qg) ? sc[c][r] * 0.125f : -INFINITY;
      }
    float pm = vals[0][0];
#pragma unroll
    for (int c = 0; c < 4; ++c)
#pragma unroll
      for (int r = 0; r < 4; ++r) pm = fmaxf(pm, vals[c][r]);
    pm = fmaxf(pm, __shfl_xor(pm, 16));
    pm = fmaxf(pm, __shfl_xor(pm, 32));
    const float mnew = fmaxf(m, pm);
    const float alpha = __expf(m - mnew);
    float psum = 0.0f;
#pragma unroll
    for (int c = 0; c < 4; ++c)
#pragma unroll
      for (int r = 0; r < 4; ++r) {
        const float p = __expf(vals[c][r] - mnew);
        vals[c][r] = p;
        psum += p;
      }
    psum += __shfl_xor(psum, 16);
    psum += __shfl_xor(psum, 32);
    l = l * alpha + psum;
    m = mnew;

#pragma unroll
    for (int c = 0; c < 4; ++c) {
      uint2 pk;
      pk.x = (unsigned)f2bf(vals[c][0]) | ((unsigned)f2bf(vals[c][1]) << 16);
      pk.y = (unsigned)f2bf(vals[c][2]) | ((unsigned)f2bf(vals[c][3]) << 16);
      *(uint2*)(Pw + lq * 144 + 32 * c + 8 * g) = pk;
    }

#pragma unroll
    for (int r = 0; r < 4; ++r) {
      const float ar = __shfl(alpha, 4 * g + r);
#pragma unroll
      for (int ht = 0; ht < 4; ++ht) o[ht][r] *= ar;
    }

#pragma unroll
    for (int ht = 0; ht < 4; ++ht) {
      const int vb = (16 * ht + lq) << 7;
#pragma unroll
      for (int s = 0; s < 2; ++s) {
        const bf16x8 pf = *(const bf16x8*)(Pw + lq * 144 + 64 * s + 16 * g);
        const bf16x8 vf = *(const bf16x8*)(VsB + ((vb + (s << 6) + (g << 4)) ^ swz));
        o[ht] = mfma16(pf, vf, o[ht]);
      }
    }
    __syncthreads();
  }

  // epilogue: split hi/lo bf16, layout (b, s, D) row-major for wo-GEMM
  const int b = bh >> 4;
  const int h = bh & 15;
#pragma unroll
  for (int r = 0; r < 4; ++r) {
    const float linv = 1.0f / __shfl(l, 4 * g + r);
    const int srow = q0 + wid * 16 + 4 * g + r;
    const size_t base = ((size_t)(b * NB_S + srow)) * NB_D + h * NB_HD;
#pragma unroll
    for (int ht = 0; ht < 4; ++ht) {
      const float v = o[ht][r] * linv;
      const ushort hi = f2bf(v);
      OH[base + 16 * ht + lq] = hi;
      OL[base + 16 * ht + lq] = f2bf(v - bf2f(hi));
    }
  }
}

extern "C" void kernel_launch(void* const* d_in, const int* in_sizes, int n_in,
                              void* d_out, int out_size, void* d_ws, size_t ws_size,
                              hipStream_t stream) {
  const float* hs = (const float*)d_in[0];
  const float* wq = (const float*)d_in[1];
  const float* wk = (const float*)d_in[2];
  const float* wv = (const float*)d_in[3];
  const float* wo = (const float*)d_in[4];
  float* out = (float*)d_out;

  const size_t E = (size_t)NB_B * NB_S * NB_D;  // 4194304
  char* w = (char*)d_ws;
  ushort* WhiA = (ushort*)w;                      // 4 x 1M = 8 MB
  ushort* WloA = WhiA + ((size_t)4 << 20);        // 8 MB
  ushort* Ahi = WloA + ((size_t)4 << 20);         // 8 MB (aliased by attn_hi)
  ushort* Alo = Ahi + E;                          // 8 MB (aliased by attn_lo)
  ushort* Qd = Alo + E;                           // 8 MB
  ushort* Kd = Qd + E;                            // 8 MB
  ushort* Vt = Kd + E;                            // 8 MB
  float* tab = (float*)(Vt + E);                  // 256 KB

  k_rope_table<<<dim3(128), 256, 0, stream>>>(tab);
  k_split<<<dim3(2048), 256, 0, stream>>>(hs, Ahi, Alo);
  k_splitw<<<dim3(512, 1, 4), 256, 0, stream>>>(wq, wk, wv, wo, WhiA, WloA);

  // Q,K projections (transposed D => lane-local rope)
  k_gemm_mfma<1><<<dim3(8, 32, 2), 256, 0, stream>>>(
      Ahi, Alo, WhiA, WloA, (void*)Qd, (void*)Kd, tab, 0);
  // V projection (normal D => pack along s for Vt)
  k_gemm_mfma<0><<<dim3(8, 32, 1), 256, 0, stream>>>(
      Ahi, Alo, WhiA + ((size_t)2 << 20), WloA + ((size_t)2 << 20),
      (void*)Vt, (void*)Vt, tab, 2);

  // attention writes split hi/lo into Ahi/Alo (dead after projections)
  k_attn<<<dim3(32, 32), 256, 0, stream>>>(Qd, Kd, Vt, Ahi, Alo);

  // output projection
  k_gemm_mfma<0><<<dim3(8, 32, 1), 256, 0, stream>>>(
      Ahi, Alo, WhiA + ((size_t)3 << 20), WloA + ((size_t)3 << 20),
      (void*)out, (void*)out, tab, 3);
}

// Round 4
// 326.049 us; speedup vs baseline: 3.7042x; 1.0996x over previous
//
#include <hip/hip_runtime.h>

#define NB_B 2
#define NB_S 2048
#define NB_D 1024
#define NB_H 16
#define NB_HD 64
#define NB_ROT 32

typedef __bf16 bf16x8 __attribute__((ext_vector_type(8)));
typedef float f32x4 __attribute__((ext_vector_type(4)));

__device__ inline f32x4 mfma16(bf16x8 a, bf16x8 b, f32x4 c) {
  return __builtin_amdgcn_mfma_f32_16x16x32_bf16(a, b, c, 0, 0, 0);
}

// float -> bf16 bits, round-to-nearest-even (finite inputs)
__device__ inline unsigned short f2bf(float f) {
  unsigned u = __builtin_bit_cast(unsigned, f);
  unsigned r = (u + 0x7fffu + ((u >> 16) & 1u)) >> 16;
  return (unsigned short)r;
}
__device__ inline float bf2f(unsigned short h) {
  return __builtin_bit_cast(float, (unsigned)h << 16);
}

// async global->LDS, 16 B per lane; lds dest = uniform base + lane*16
__device__ inline void async16(const void* g, void* l) {
  __builtin_amdgcn_global_load_lds((const __attribute__((address_space(1))) unsigned int*)g,
                                   (__attribute__((address_space(3))) unsigned int*)l, 16, 0, 0);
}

// ---------------- RoPE sin/cos table ----------------
__global__ void k_rope_table(float* __restrict__ tab) {
  int i = blockIdx.x * blockDim.x + threadIdx.x;
  const int NP = NB_S * (NB_ROT / 2);
  if (i >= NP) return;
  int s = i >> 4;
  int p = i & 15;
  float inv = powf(10000.0f, -(2.0f * (float)p) / (float)NB_ROT);
  float a = (float)s * inv;
  tab[2 * i + 0] = sinf(a);
  tab[2 * i + 1] = cosf(a);
}

// ---------------- fp32 -> bf16 hi/lo split (8 elems/thread) ----------------
__global__ __launch_bounds__(256) void k_split(const float* __restrict__ src,
                                               ushort* __restrict__ hi,
                                               ushort* __restrict__ lo) {
  const int i = (blockIdx.x * 256 + threadIdx.x) * 8;
  float4 a = *(const float4*)(src + i);
  float4 b = *(const float4*)(src + i + 4);
  float v[8] = {a.x, a.y, a.z, a.w, b.x, b.y, b.z, b.w};
  ushort h[8], l[8];
#pragma unroll
  for (int j = 0; j < 8; ++j) {
    h[j] = f2bf(v[j]);
    l[j] = f2bf(v[j] - bf2f(h[j]));
  }
  ushort4 h0 = {h[0], h[1], h[2], h[3]}, h1 = {h[4], h[5], h[6], h[7]};
  ushort4 l0 = {l[0], l[1], l[2], l[3]}, l1 = {l[4], l[5], l[6], l[7]};
  *(ushort4*)(hi + i) = h0; *(ushort4*)(hi + i + 4) = h1;
  *(ushort4*)(lo + i) = l0; *(ushort4*)(lo + i + 4) = l1;
}

__global__ __launch_bounds__(256) void k_splitw(
    const float* __restrict__ s0, const float* __restrict__ s1,
    const float* __restrict__ s2, const float* __restrict__ s3,
    ushort* __restrict__ hi, ushort* __restrict__ lo) {
  const int z = blockIdx.z;
  const float* src = (z == 0) ? s0 : (z == 1) ? s1 : (z == 2) ? s2 : s3;
  ushort* h = hi + ((size_t)z << 20);
  ushort* l = lo + ((size_t)z << 20);
  const int i = (blockIdx.x * 256 + threadIdx.x) * 8;
  float4 a = *(const float4*)(src + i);
  float4 b = *(const float4*)(src + i + 4);
  float v[8] = {a.x, a.y, a.z, a.w, b.x, b.y, b.z, b.w};
  ushort hh[8], ll[8];
#pragma unroll
  for (int j = 0; j < 8; ++j) {
    hh[j] = f2bf(v[j]);
    ll[j] = f2bf(v[j] - bf2f(hh[j]));
  }
  ushort4 h0 = {hh[0], hh[1], hh[2], hh[3]}, h1 = {hh[4], hh[5], hh[6], hh[7]};
  ushort4 l0 = {ll[0], ll[1], ll[2], ll[3]}, l1 = {ll[4], ll[5], ll[6], ll[7]};
  *(ushort4*)(h + i) = h0; *(ushort4*)(h + i + 4) = h1;
  *(ushort4*)(l + i) = l0; *(ushort4*)(l + i + 4) = l1;
}

// ---------------- split-bf16 MFMA GEMM  C = A @ W^T ----------------
// 128x128 tile, BK=32, 4 waves x (64x64). Fragment-order LDS (conflict-free).
// TR=0: D[m][n]  (V: mode 2 -> bf16 Vt (bh,hd,S);  wo: mode 3 -> fp32 row-major)
// TR=1: D[n][m]  (Q/K: rope lane-local -> bf16 (bh,s,hd); Q pre-scaled 1/8)
template <int TR>
__global__ __launch_bounds__(256) void k_gemm_mfma(
    const ushort* __restrict__ Ahi, const ushort* __restrict__ Alo,
    const ushort* __restrict__ Whi, const ushort* __restrict__ Wlo,
    void* __restrict__ O0, void* __restrict__ O1,
    const float* __restrict__ tab, int mode_base) {
  __shared__ __align__(16) ushort AhS[4096];
  __shared__ __align__(16) ushort AlS[4096];
  __shared__ __align__(16) ushort WhS[4096];
  __shared__ __align__(16) ushort WlS[4096];

  const int tid = threadIdx.x;
  const int wid = tid >> 6;
  const int lane = tid & 63;
  const int lq = lane & 15;
  const int g = lane >> 4;

  const int z = blockIdx.z;
  const int mode = mode_base + z;
  const ushort* wh = Whi + ((size_t)z << 20);
  const ushort* wl = Wlo + ((size_t)z << 20);
  void* O = (z == 0) ? O0 : O1;

  // XCD-aware remap: all 8 n-blocks of an m-panel land on one XCD
  const int p = blockIdx.x + 8 * blockIdx.y;
  const int xcd = p & 7;
  const int jj = p >> 3;
  const int m0 = (4 * xcd + (jj >> 3)) * 128;
  const int n0 = (jj & 7) * 128;

  // wave wid stages the whole region {0:Ah, 1:Al, 2:Wh, 3:Wl}
  const ushort* gsb;
  ushort* lsb;
  int rowb;
  if (wid == 0)      { gsb = Ahi; rowb = m0; lsb = AhS; }
  else if (wid == 1) { gsb = Alo; rowb = m0; lsb = AlS; }
  else if (wid == 2) { gsb = wh;  rowb = n0; lsb = WhS; }
  else               { gsb = wl;  rowb = n0; lsb = WlS; }
  const ushort* gp = gsb + (size_t)(rowb + lq) * NB_D + g * 8;

  f32x4 acc[4][4];
#pragma unroll
  for (int i = 0; i < 4; ++i)
#pragma unroll
    for (int j = 0; j < 4; ++j) acc[i][j] = (f32x4){0.f, 0.f, 0.f, 0.f};

  const int ma = (wid & 1) * 4;
  const int nb = (wid >> 1) * 4;

  for (int k0 = 0; k0 < NB_D; k0 += 32) {
#pragma unroll
    for (int j = 0; j < 8; ++j)
      async16((const void*)(gp + (size_t)j * 16 * NB_D + k0), (void*)(lsb + j * 512));
    __syncthreads();

    bf16x8 fah[4], fal[4], fwh[4], fwl[4];
#pragma unroll
    for (int i = 0; i < 4; ++i) {
      fah[i] = *(const bf16x8*)(AhS + (ma + i) * 512 + lane * 8);
      fal[i] = *(const bf16x8*)(AlS + (ma + i) * 512 + lane * 8);
      fwh[i] = *(const bf16x8*)(WhS + (nb + i) * 512 + lane * 8);
      fwl[i] = *(const bf16x8*)(WlS + (nb + i) * 512 + lane * 8);
    }
    __builtin_amdgcn_s_setprio(1);
#pragma unroll
    for (int i = 0; i < 4; ++i)
#pragma unroll
      for (int j = 0; j < 4; ++j) {
        if (TR == 0) {
          f32x4 c = acc[i][j];
          c = mfma16(fah[i], fwh[j], c);
          c = mfma16(fah[i], fwl[j], c);
          c = mfma16(fal[i], fwh[j], c);
          acc[i][j] = c;
        } else {
          f32x4 c = acc[j][i];
          c = mfma16(fwh[j], fah[i], c);
          c = mfma16(fwh[j], fal[i], c);
          c = mfma16(fwl[j], fah[i], c);
          acc[j][i] = c;
        }
      }
    __builtin_amdgcn_s_setprio(0);
    __syncthreads();
  }

  const int wm = (wid & 1) * 64;
  const int wn = (wid >> 1) * 64;

  if (TR == 0) {
    if (mode == 3) {
      float* out = (float*)O;
#pragma unroll
      for (int i = 0; i < 4; ++i)
#pragma unroll
        for (int j = 0; j < 4; ++j) {
          const int col = n0 + wn + j * 16 + lq;
#pragma unroll
          for (int r = 0; r < 4; ++r) {
            const int row = m0 + wm + i * 16 + 4 * g + r;
            out[(size_t)row * NB_D + col] = acc[i][j][r];
          }
        }
    } else {  // V -> bf16 transposed (bh, hd, S)
      ushort* ov = (ushort*)O;
#pragma unroll
      for (int i = 0; i < 4; ++i) {
        const int gm0 = m0 + wm + i * 16 + 4 * g;
        const int b = gm0 >> 11;
        const int s0 = gm0 & (NB_S - 1);
#pragma unroll
        for (int j = 0; j < 4; ++j) {
          const int gn = n0 + wn + j * 16 + lq;
          const int hh = gn >> 6;
          const int d0 = gn & 63;
          ushort4 pk = {f2bf(acc[i][j][0]), f2bf(acc[i][j][1]),
                        f2bf(acc[i][j][2]), f2bf(acc[i][j][3])};
          *(ushort4*)(ov + ((size_t)((b * NB_H + hh) * NB_HD + d0)) * NB_S + s0) = pk;
        }
      }
    }
  } else {  // TR==1: Q/K, rope lane-local, bf16 (bh, s, hd); Q scaled 1/8
#pragma unroll
    for (int jn = 0; jn < 4; ++jn) {
      const int gn0 = n0 + wn + jn * 16 + 4 * g;
      const int hh = gn0 >> 6;
      const int d0 = gn0 & 63;
#pragma unroll
      for (int im = 0; im < 4; ++im) {
        const int gm = m0 + wm + im * 16 + lq;
        const int b = gm >> 11;
        const int s = gm & (NB_S - 1);
        float v0 = acc[jn][im][0], v1 = acc[jn][im][1];
        float v2 = acc[jn][im][2], v3 = acc[jn][im][3];
        if (d0 < NB_ROT) {
          const int p0 = d0 >> 1;
          const float2 t0 = *(const float2*)(tab + ((s * 16 + p0) << 1));
          const float2 t1 = *(const float2*)(tab + ((s * 16 + p0 + 1) << 1));
          const float n0v = v0 * t0.y - v1 * t0.x;
          const float n1v = v1 * t0.y + v0 * t0.x;
          const float n2v = v2 * t1.y - v3 * t1.x;
          const float n3v = v3 * t1.y + v2 * t1.x;
          v0 = n0v; v1 = n1v; v2 = n2v; v3 = n3v;
        }
        if (mode == 0) { v0 *= 0.125f; v1 *= 0.125f; v2 *= 0.125f; v3 *= 0.125f; }
        ushort4 pk = {f2bf(v0), f2bf(v1), f2bf(v2), f2bf(v3)};
        *(ushort4*)((ushort*)O + ((size_t)(b * NB_H + hh) * NB_S + s) * NB_HD + d0) = pk;
      }
    }
  }
}

// ---------------- bf16 MFMA causal flash attention ----------------
// 4 waves x 16 q-rows; KVBLK=64; double-buffered async K/V staging
// (pre-swizzled global src, linear LDS dest); diagonal-only masking;
// defer-max (THR=8); XCD-balanced (qt,bh) mapping. Q pre-scaled by 1/8.
__global__ __launch_bounds__(256) void k_attn(
    const ushort* __restrict__ Q, const ushort* __restrict__ K,
    const ushort* __restrict__ Vt, ushort* __restrict__ OH,
    ushort* __restrict__ OL) {
  __shared__ __align__(16) unsigned char KsB[2][8192];  // [kk][hd] bf16, swz
  __shared__ __align__(16) unsigned char VsB[2][8192];  // [hd][kk] bf16, swz
  __shared__ __align__(16) unsigned char PsB[8192];     // 4w x [16 q][64 k] bf16, swz

  const int tid = threadIdx.x;
  const int wid = tid >> 6;
  const int lane = tid & 63;
  const int lq = lane & 15;
  const int g = lane >> 4;

  // XCD-balanced mapping: 4 same-bh blocks per CU, qt-set sums to 66
  const int p = blockIdx.x + 32 * blockIdx.y;
  const int xcd = p & 7;
  const int q = p >> 3;
  const int bh = 4 * xcd + (q & 3);
  const int qi = q >> 2;
  const int hi = qi >> 3, lo = qi & 7;
  const int qt = (hi == 0) ? lo : (hi == 1) ? 31 - lo : (hi == 2) ? 8 + lo : 23 - lo;

  const int q0 = qt * 64;
  const int qg = q0 + wid * 16 + lq;

  const ushort* Kb = K + (size_t)bh * NB_S * NB_HD;
  const ushort* Vb = Vt + (size_t)bh * NB_HD * NB_S;

  const ushort* Qrow = Q + ((size_t)bh * NB_S + qg) * NB_HD;
  const bf16x8 qf0 = *(const bf16x8*)(Qrow + 8 * g);
  const bf16x8 qf1 = *(const bf16x8*)(Qrow + 32 + 8 * g);

  // staging geometry: instr j covers rows 16*wid+8*j .. +7, lane -> (row, chunk)
  const int srow = lane >> 3;                 // 0..7
  const int schk = (lane & 7) ^ srow;         // pre-swizzled source chunk

  float m = -INFINITY;
  float l = 0.0f;
  f32x4 o[4];
#pragma unroll
  for (int ht = 0; ht < 4; ++ht) o[ht] = (f32x4){0.f, 0.f, 0.f, 0.f};

  const int swz = (lq & 7) << 4;
  unsigned char* Pw = PsB + wid * 2048;

  // prologue: stage tile 0 into buffer 0
#pragma unroll
  for (int j = 0; j < 2; ++j) {
    const int rb = 16 * wid + 8 * j;
    const int row = rb + srow;
    async16(Kb + (size_t)row * NB_HD + schk * 8, KsB[0] + rb * 128);
    async16(Vb + (size_t)row * NB_S + schk * 8, VsB[0] + rb * 128);
  }
  __syncthreads();

  for (int t = 0; t <= qt; ++t) {
    const int cur = t & 1;
    if (t < qt) {  // prefetch next tile into the other buffer
      const int k1 = (t + 1) * 64;
#pragma unroll
      for (int j = 0; j < 2; ++j) {
        const int rb = 16 * wid + 8 * j;
        const int row = rb + srow;
        async16(Kb + (size_t)(k1 + row) * NB_HD + schk * 8, KsB[cur ^ 1] + rb * 128);
        async16(Vb + (size_t)row * NB_S + k1 + schk * 8, VsB[cur ^ 1] + rb * 128);
      }
    }
    const unsigned char* Ks = KsB[cur];
    const unsigned char* Vs = VsB[cur];

    // ---- S^T = K * Q^T : lane owns q-col lq, k-rows 16c+4g+r ----
    f32x4 sc[4];
    __builtin_amdgcn_s_setprio(1);
#pragma unroll
    for (int c = 0; c < 4; ++c) {
      const int rb = (16 * c + lq) << 7;
      const bf16x8 a0 = *(const bf16x8*)(Ks + ((rb + (g << 4)) ^ swz));
      const bf16x8 a1 = *(const bf16x8*)(Ks + ((rb + 64 + (g << 4)) ^ swz));
      f32x4 zz = {0.f, 0.f, 0.f, 0.f};
      zz = mfma16(a0, qf0, zz);
      zz = mfma16(a1, qf1, zz);
      sc[c] = zz;
    }
    __builtin_amdgcn_s_setprio(0);

    float vals[4][4];
    if (t == qt) {  // only the diagonal tile needs the causal mask
      const int k0 = t * 64;
#pragma unroll
      for (int c = 0; c < 4; ++c)
#pragma unroll
        for (int r = 0; r < 4; ++r) {
          const int kk = k0 + 16 * c + 4 * g + r;
          vals[c][r] = (kk <= qg) ? sc[c][r] : -INFINITY;
        }
    } else {
#pragma unroll
      for (int c = 0; c < 4; ++c)
#pragma unroll
        for (int r = 0; r < 4; ++r) vals[c][r] = sc[c][r];
    }

    float pm = vals[0][0];
#pragma unroll
    for (int c = 0; c < 4; ++c)
#pragma unroll
      for (int r = 0; r < 4; ++r) pm = fmaxf(pm, vals[c][r]);
    pm = fmaxf(pm, __shfl_xor(pm, 16));
    pm = fmaxf(pm, __shfl_xor(pm, 32));

    float psum = 0.0f;
    if (__any(pm - m > 8.0f)) {  // full online-softmax rescale path
      const float mnew = fmaxf(m, pm);
      const float alpha = __expf(m - mnew);
#pragma unroll
      for (int c = 0; c < 4; ++c)
#pragma unroll
        for (int r = 0; r < 4; ++r) {
          const float pv = __expf(vals[c][r] - mnew);
          vals[c][r] = pv;
          psum += pv;
        }
      psum += __shfl_xor(psum, 16);
      psum += __shfl_xor(psum, 32);
      l = l * alpha + psum;
      m = mnew;
#pragma unroll
      for (int r = 0; r < 4; ++r) {
        const float ar = __shfl(alpha, 4 * g + r);
#pragma unroll
        for (int ht = 0; ht < 4; ++ht) o[ht][r] *= ar;
      }
    } else {  // defer-max: keep m, skip rescale (p bounded by e^8)
#pragma unroll
      for (int c = 0; c < 4; ++c)
#pragma unroll
        for (int r = 0; r < 4; ++r) {
          const float pv = __expf(vals[c][r] - m);
          vals[c][r] = pv;
          psum += pv;
        }
      psum += __shfl_xor(psum, 16);
      psum += __shfl_xor(psum, 32);
      l += psum;
    }

    // ---- P -> LDS bf16 (swizzled, per-wave [16][64]) ----
#pragma unroll
    for (int c = 0; c < 4; ++c) {
      uint2 pk;
      pk.x = (unsigned)f2bf(vals[c][0]) | ((unsigned)f2bf(vals[c][1]) << 16);
      pk.y = (unsigned)f2bf(vals[c][2]) | ((unsigned)f2bf(vals[c][3]) << 16);
      *(uint2*)(Pw + lq * 128 + ((32 * c + 8 * g) ^ swz)) = pk;
    }

    // ---- PV: O[q][hd] += P * V ----
    __builtin_amdgcn_s_setprio(1);
#pragma unroll
    for (int ht = 0; ht < 4; ++ht) {
      const int vb = (16 * ht + lq) << 7;
#pragma unroll
      for (int s = 0; s < 2; ++s) {
        const bf16x8 pf = *(const bf16x8*)(Pw + lq * 128 + ((64 * s + 16 * g) ^ swz));
        const bf16x8 vf = *(const bf16x8*)(Vs + ((vb + (s << 6) + (g << 4)) ^ swz));
        o[ht] = mfma16(pf, vf, o[ht]);
      }
    }
    __builtin_amdgcn_s_setprio(0);

    __syncthreads();  // drains vmcnt (next tile landed) + publishes P/KV reuse
  }

  // epilogue: divide by l, split hi/lo bf16, layout (b, s, D)
  const int b = bh >> 4;
  const int h = bh & 15;
#pragma unroll
  for (int r = 0; r < 4; ++r) {
    const float linv = 1.0f / __shfl(l, 4 * g + r);
    const int srw = q0 + wid * 16 + 4 * g + r;
    const size_t base = ((size_t)(b * NB_S + srw)) * NB_D + h * NB_HD;
#pragma unroll
    for (int ht = 0; ht < 4; ++ht) {
      const float v = o[ht][r] * linv;
      const ushort hv = f2bf(v);
      OH[base + 16 * ht + lq] = hv;
      OL[base + 16 * ht + lq] = f2bf(v - bf2f(hv));
    }
  }
}

extern "C" void kernel_launch(void* const* d_in, const int* in_sizes, int n_in,
                              void* d_out, int out_size, void* d_ws, size_t ws_size,
                              hipStream_t stream) {
  const float* hs = (const float*)d_in[0];
  const float* wq = (const float*)d_in[1];
  const float* wk = (const float*)d_in[2];
  const float* wv = (const float*)d_in[3];
  const float* wo = (const float*)d_in[4];
  float* out = (float*)d_out;

  const size_t E = (size_t)NB_B * NB_S * NB_D;  // 4194304
  char* w = (char*)d_ws;
  ushort* WhiA = (ushort*)w;
  ushort* WloA = WhiA + ((size_t)4 << 20);
  ushort* Ahi = WloA + ((size_t)4 << 20);
  ushort* Alo = Ahi + E;
  ushort* Qd = Alo + E;
  ushort* Kd = Qd + E;
  ushort* Vt = Kd + E;
  float* tab = (float*)(Vt + E);

  k_rope_table<<<dim3(128), 256, 0, stream>>>(tab);
  k_split<<<dim3(2048), 256, 0, stream>>>(hs, Ahi, Alo);
  k_splitw<<<dim3(512, 1, 4), 256, 0, stream>>>(wq, wk, wv, wo, WhiA, WloA);

  // Q,K projections (transposed D => lane-local rope; Q pre-scaled 1/8)
  k_gemm_mfma<1><<<dim3(8, 32, 2), 256, 0, stream>>>(
      Ahi, Alo, WhiA, WloA, (void*)Qd, (void*)Kd, tab, 0);
  // V projection (normal D => pack along s for Vt)
  k_gemm_mfma<0><<<dim3(8, 32, 1), 256, 0, stream>>>(
      Ahi, Alo, WhiA + ((size_t)2 << 20), WloA + ((size_t)2 << 20),
      (void*)Vt, (void*)Vt, tab, 2);

  // attention writes split hi/lo into Ahi/Alo (dead after projections)
  k_attn<<<dim3(32, 32), 256, 0, stream>>>(Qd, Kd, Vt, Ahi, Alo);

  // output projection
  k_gemm_mfma<0><<<dim3(8, 32, 1), 256, 0, stream>>>(
      Ahi, Alo, WhiA + ((size_t)3 << 20), WloA + ((size_t)3 << 20),
      (void*)out, (void*)out, tab, 3);
}

// Round 5
// 279.265 us; speedup vs baseline: 4.3248x; 1.1675x over previous
//
#include <hip/hip_runtime.h>

#define NB_B 2
#define NB_S 2048
#define NB_D 1024
#define NB_H 16
#define NB_HD 64
#define NB_ROT 32

typedef __bf16 bf16x8 __attribute__((ext_vector_type(8)));
typedef float f32x4 __attribute__((ext_vector_type(4)));

__device__ inline f32x4 mfma16(bf16x8 a, bf16x8 b, f32x4 c) {
  return __builtin_amdgcn_mfma_f32_16x16x32_bf16(a, b, c, 0, 0, 0);
}

// float -> bf16 bits, round-to-nearest-even (finite inputs)
__device__ inline unsigned short f2bf(float f) {
  unsigned u = __builtin_bit_cast(unsigned, f);
  unsigned r = (u + 0x7fffu + ((u >> 16) & 1u)) >> 16;
  return (unsigned short)r;
}
__device__ inline float bf2f(unsigned short h) {
  return __builtin_bit_cast(float, (unsigned)h << 16);
}

// async global->LDS, 16 B per lane; lds dest = uniform base + lane*16
__device__ inline void async16(const void* g, void* l) {
  __builtin_amdgcn_global_load_lds((const __attribute__((address_space(1))) unsigned int*)g,
                                   (__attribute__((address_space(3))) unsigned int*)l, 16, 0, 0);
}

// ---------------- RoPE sin/cos table ----------------
__global__ void k_rope_table(float* __restrict__ tab) {
  int i = blockIdx.x * blockDim.x + threadIdx.x;
  const int NP = NB_S * (NB_ROT / 2);
  if (i >= NP) return;
  int s = i >> 4;
  int p = i & 15;
  float inv = powf(10000.0f, -(2.0f * (float)p) / (float)NB_ROT);
  float a = (float)s * inv;
  tab[2 * i + 0] = sinf(a);
  tab[2 * i + 1] = cosf(a);
}

// ---------------- fp32 -> bf16 hi/lo split (8 elems/thread) ----------------
__global__ __launch_bounds__(256) void k_split(const float* __restrict__ src,
                                               ushort* __restrict__ hi,
                                               ushort* __restrict__ lo) {
  const int i = (blockIdx.x * 256 + threadIdx.x) * 8;
  float4 a = *(const float4*)(src + i);
  float4 b = *(const float4*)(src + i + 4);
  float v[8] = {a.x, a.y, a.z, a.w, b.x, b.y, b.z, b.w};
  ushort h[8], l[8];
#pragma unroll
  for (int j = 0; j < 8; ++j) {
    h[j] = f2bf(v[j]);
    l[j] = f2bf(v[j] - bf2f(h[j]));
  }
  ushort4 h0 = {h[0], h[1], h[2], h[3]}, h1 = {h[4], h[5], h[6], h[7]};
  ushort4 l0 = {l[0], l[1], l[2], l[3]}, l1 = {l[4], l[5], l[6], l[7]};
  *(ushort4*)(hi + i) = h0; *(ushort4*)(hi + i + 4) = h1;
  *(ushort4*)(lo + i) = l0; *(ushort4*)(lo + i + 4) = l1;
}

__global__ __launch_bounds__(256) void k_splitw(
    const float* __restrict__ s0, const float* __restrict__ s1,
    const float* __restrict__ s2, const float* __restrict__ s3,
    ushort* __restrict__ hi, ushort* __restrict__ lo) {
  const int z = blockIdx.z;
  const float* src = (z == 0) ? s0 : (z == 1) ? s1 : (z == 2) ? s2 : s3;
  ushort* h = hi + ((size_t)z << 20);
  ushort* l = lo + ((size_t)z << 20);
  const int i = (blockIdx.x * 256 + threadIdx.x) * 8;
  float4 a = *(const float4*)(src + i);
  float4 b = *(const float4*)(src + i + 4);
  float v[8] = {a.x, a.y, a.z, a.w, b.x, b.y, b.z, b.w};
  ushort hh[8], ll[8];
#pragma unroll
  for (int j = 0; j < 8; ++j) {
    hh[j] = f2bf(v[j]);
    ll[j] = f2bf(v[j] - bf2f(hh[j]));
  }
  ushort4 h0 = {hh[0], hh[1], hh[2], hh[3]}, h1 = {hh[4], hh[5], hh[6], hh[7]};
  ushort4 l0 = {ll[0], ll[1], ll[2], ll[3]}, l1 = {ll[4], ll[5], ll[6], ll[7]};
  *(ushort4*)(h + i) = h0; *(ushort4*)(h + i + 4) = h1;
  *(ushort4*)(l + i) = l0; *(ushort4*)(l + i + 4) = l1;
}

// ---------------- one K-step of the split-bf16 MFMA tile ----------------
// base: LDS buffer {Ah[4096], Al[4096], Wh[4096], Wl[4096]} fragment-order.
// TRC=0: acc[m][n] = A*W^T ;  TRC=1: acc[n][m] = (W*A^T) (operand swap)
template <int TRC>
__device__ __forceinline__ void gemm_step(const ushort* base, int ma, int nb,
                                          int lane, f32x4 (&acc)[4][4]) {
  bf16x8 fah[4], fal[4], fwh[4], fwl[4];
#pragma unroll
  for (int i = 0; i < 4; ++i) {
    fah[i] = *(const bf16x8*)(base + (ma + i) * 512 + lane * 8);
    fal[i] = *(const bf16x8*)(base + 4096 + (ma + i) * 512 + lane * 8);
    fwh[i] = *(const bf16x8*)(base + 8192 + (nb + i) * 512 + lane * 8);
    fwl[i] = *(const bf16x8*)(base + 12288 + (nb + i) * 512 + lane * 8);
  }
  __builtin_amdgcn_s_setprio(1);
#pragma unroll
  for (int i = 0; i < 4; ++i)
#pragma unroll
    for (int j = 0; j < 4; ++j) {
      if (TRC == 0) {
        f32x4 c = acc[i][j];
        c = mfma16(fah[i], fwh[j], c);
        c = mfma16(fah[i], fwl[j], c);
        c = mfma16(fal[i], fwh[j], c);
        acc[i][j] = c;
      } else {
        f32x4 c = acc[j][i];
        c = mfma16(fwh[j], fah[i], c);
        c = mfma16(fwh[j], fal[i], c);
        c = mfma16(fwl[j], fah[i], c);
        acc[j][i] = c;
      }
    }
  __builtin_amdgcn_s_setprio(0);
}

// ---------------- split-bf16 MFMA GEMM  C = A @ W^T (merged, dbuf) ----------------
// NZ weight matrices in one dispatch (grid = NZ*256 blocks).
// modes: 0=Q (rope+1/8, bf16 (bh,s,hd))  1=K (rope, bf16 (bh,s,hd))
//        2=V (bf16 Vt (bh,hd,S))         3=wo (fp32 row-major)
template <int NZ>
__global__ __launch_bounds__(256) void k_gemm_mfma(
    const ushort* __restrict__ Ahi, const ushort* __restrict__ Alo,
    const ushort* __restrict__ Whi, const ushort* __restrict__ Wlo,
    void* __restrict__ O0, void* __restrict__ O1, void* __restrict__ O2,
    const float* __restrict__ tab, int mode_base) {
  __shared__ __align__(16) ushort SB[2][4][4096];  // 64 KB, dbuf x {Ah,Al,Wh,Wl}

  const int tid = threadIdx.x;
  const int wid = tid >> 6;
  const int lane = tid & 63;
  const int lq = lane & 15;
  const int g = lane >> 4;

  // XCD-aware mapping: the 8*NZ blocks sharing one A-panel land on one XCD
  const int p = blockIdx.x;
  const int xcd = p & 7;
  const int j = p >> 3;
  const int group = j / (8 * NZ);
  const int rem = j % (8 * NZ);
  const int z = rem >> 3;
  const int n0 = (rem & 7) << 7;
  const int m0 = ((xcd << 2) + group) << 7;

  const int mode = mode_base + z;
  const bool tr = (mode <= 1);
  const ushort* wh = Whi + ((size_t)z << 20);
  const ushort* wl = Wlo + ((size_t)z << 20);
  void* O = (z == 0) ? O0 : (z == 1) ? O1 : O2;

  // wave wid stages one region {0:Ah, 1:Al, 2:Wh, 3:Wl}
  const ushort* gsb;
  int rowb;
  if (wid == 0)      { gsb = Ahi; rowb = m0; }
  else if (wid == 1) { gsb = Alo; rowb = m0; }
  else if (wid == 2) { gsb = wh;  rowb = n0; }
  else               { gsb = wl;  rowb = n0; }
  const ushort* gp = gsb + (size_t)(rowb + lq) * NB_D + g * 8;

  f32x4 acc[4][4];
#pragma unroll
  for (int i = 0; i < 4; ++i)
#pragma unroll
    for (int jj = 0; jj < 4; ++jj) acc[i][jj] = (f32x4){0.f, 0.f, 0.f, 0.f};

  const int ma = (wid & 1) * 4;
  const int nb = (wid >> 1) * 4;

  // prologue: stage k0=0 into buffer 0
#pragma unroll
  for (int jj = 0; jj < 8; ++jj)
    async16(gp + (size_t)jj * 16 * NB_D, &SB[0][wid][jj * 512]);
  __syncthreads();

  for (int k0 = 0; k0 < NB_D; k0 += 32) {
    const int cur = (k0 >> 5) & 1;
    if (k0 + 32 < NB_D) {  // prefetch next K-tile into the other buffer
      const ushort* gpn = gp + k0 + 32;
#pragma unroll
      for (int jj = 0; jj < 8; ++jj)
        async16(gpn + (size_t)jj * 16 * NB_D, &SB[cur ^ 1][wid][jj * 512]);
    }
    const ushort* base = &SB[cur][0][0];
    if (tr) gemm_step<1>(base, ma, nb, lane, acc);
    else    gemm_step<0>(base, ma, nb, lane, acc);
    __syncthreads();  // next tile landed (vmcnt drain after full compute phase)
  }

  const int wm = (wid & 1) * 64;
  const int wn = (wid >> 1) * 64;

  if (mode == 3) {
    float* out = (float*)O;
#pragma unroll
    for (int i = 0; i < 4; ++i)
#pragma unroll
      for (int jj = 0; jj < 4; ++jj) {
        const int col = n0 + wn + jj * 16 + lq;
#pragma unroll
        for (int r = 0; r < 4; ++r) {
          const int row = m0 + wm + i * 16 + 4 * g + r;
          out[(size_t)row * NB_D + col] = acc[i][jj][r];
        }
      }
  } else if (mode == 2) {  // V -> bf16 transposed (bh, hd, S)
    ushort* ov = (ushort*)O;
#pragma unroll
    for (int i = 0; i < 4; ++i) {
      const int gm0 = m0 + wm + i * 16 + 4 * g;
      const int b = gm0 >> 11;
      const int s0 = gm0 & (NB_S - 1);
#pragma unroll
      for (int jj = 0; jj < 4; ++jj) {
        const int gn = n0 + wn + jj * 16 + lq;
        const int hh = gn >> 6;
        const int d0 = gn & 63;
        ushort4 pk = {f2bf(acc[i][jj][0]), f2bf(acc[i][jj][1]),
                      f2bf(acc[i][jj][2]), f2bf(acc[i][jj][3])};
        *(ushort4*)(ov + ((size_t)((b * NB_H + hh) * NB_HD + d0)) * NB_S + s0) = pk;
      }
    }
  } else {  // Q/K: rope lane-local, bf16 (bh, s, hd); Q scaled 1/8
#pragma unroll
    for (int jn = 0; jn < 4; ++jn) {
      const int gn0 = n0 + wn + jn * 16 + 4 * g;
      const int hh = gn0 >> 6;
      const int d0 = gn0 & 63;
#pragma unroll
      for (int im = 0; im < 4; ++im) {
        const int gm = m0 + wm + im * 16 + lq;
        const int b = gm >> 11;
        const int s = gm & (NB_S - 1);
        float v0 = acc[jn][im][0], v1 = acc[jn][im][1];
        float v2 = acc[jn][im][2], v3 = acc[jn][im][3];
        if (d0 < NB_ROT) {
          const int p0 = d0 >> 1;
          const float2 t0 = *(const float2*)(tab + ((s * 16 + p0) << 1));
          const float2 t1 = *(const float2*)(tab + ((s * 16 + p0 + 1) << 1));
          const float n0v = v0 * t0.y - v1 * t0.x;
          const float n1v = v1 * t0.y + v0 * t0.x;
          const float n2v = v2 * t1.y - v3 * t1.x;
          const float n3v = v3 * t1.y + v2 * t1.x;
          v0 = n0v; v1 = n1v; v2 = n2v; v3 = n3v;
        }
        if (mode == 0) { v0 *= 0.125f; v1 *= 0.125f; v2 *= 0.125f; v3 *= 0.125f; }
        ushort4 pk = {f2bf(v0), f2bf(v1), f2bf(v2), f2bf(v3)};
        *(ushort4*)((ushort*)O + ((size_t)(b * NB_H + hh) * NB_S + s) * NB_HD + d0) = pk;
      }
    }
  }
}

// ---------------- bf16 MFMA causal flash attention ----------------
// 4 waves x 16 q-rows; KVBLK=64; double-buffered async K/V staging
// (pre-swizzled global src, linear LDS dest); diagonal-only masking;
// defer-max (THR=8); XCD-balanced (qt,bh) mapping. Q pre-scaled by 1/8.
__global__ __launch_bounds__(256) void k_attn(
    const ushort* __restrict__ Q, const ushort* __restrict__ K,
    const ushort* __restrict__ Vt, ushort* __restrict__ OH,
    ushort* __restrict__ OL) {
  __shared__ __align__(16) unsigned char KsB[2][8192];  // [kk][hd] bf16, swz
  __shared__ __align__(16) unsigned char VsB[2][8192];  // [hd][kk] bf16, swz
  __shared__ __align__(16) unsigned char PsB[8192];     // 4w x [16 q][64 k] bf16, swz

  const int tid = threadIdx.x;
  const int wid = tid >> 6;
  const int lane = tid & 63;
  const int lq = lane & 15;
  const int g = lane >> 4;

  // XCD-balanced mapping: 4 same-bh blocks per CU, qt-set sums to 66
  const int p = blockIdx.x + 32 * blockIdx.y;
  const int xcd = p & 7;
  const int q = p >> 3;
  const int bh = 4 * xcd + (q & 3);
  const int qi = q >> 2;
  const int hi = qi >> 3, lo = qi & 7;
  const int qt = (hi == 0) ? lo : (hi == 1) ? 31 - lo : (hi == 2) ? 8 + lo : 23 - lo;

  const int q0 = qt * 64;
  const int qg = q0 + wid * 16 + lq;

  const ushort* Kb = K + (size_t)bh * NB_S * NB_HD;
  const ushort* Vb = Vt + (size_t)bh * NB_HD * NB_S;

  const ushort* Qrow = Q + ((size_t)bh * NB_S + qg) * NB_HD;
  const bf16x8 qf0 = *(const bf16x8*)(Qrow + 8 * g);
  const bf16x8 qf1 = *(const bf16x8*)(Qrow + 32 + 8 * g);

  const int srow = lane >> 3;
  const int schk = (lane & 7) ^ srow;

  float m = -INFINITY;
  float l = 0.0f;
  f32x4 o[4];
#pragma unroll
  for (int ht = 0; ht < 4; ++ht) o[ht] = (f32x4){0.f, 0.f, 0.f, 0.f};

  const int swz = (lq & 7) << 4;
  unsigned char* Pw = PsB + wid * 2048;

#pragma unroll
  for (int j = 0; j < 2; ++j) {
    const int rb = 16 * wid + 8 * j;
    const int row = rb + srow;
    async16(Kb + (size_t)row * NB_HD + schk * 8, KsB[0] + rb * 128);
    async16(Vb + (size_t)row * NB_S + schk * 8, VsB[0] + rb * 128);
  }
  __syncthreads();

  for (int t = 0; t <= qt; ++t) {
    const int cur = t & 1;
    if (t < qt) {
      const int k1 = (t + 1) * 64;
#pragma unroll
      for (int j = 0; j < 2; ++j) {
        const int rb = 16 * wid + 8 * j;
        const int row = rb + srow;
        async16(Kb + (size_t)(k1 + row) * NB_HD + schk * 8, KsB[cur ^ 1] + rb * 128);
        async16(Vb + (size_t)row * NB_S + k1 + schk * 8, VsB[cur ^ 1] + rb * 128);
      }
    }
    const unsigned char* Ks = KsB[cur];
    const unsigned char* Vs = VsB[cur];

    f32x4 sc[4];
    __builtin_amdgcn_s_setprio(1);
#pragma unroll
    for (int c = 0; c < 4; ++c) {
      const int rb = (16 * c + lq) << 7;
      const bf16x8 a0 = *(const bf16x8*)(Ks + ((rb + (g << 4)) ^ swz));
      const bf16x8 a1 = *(const bf16x8*)(Ks + ((rb + 64 + (g << 4)) ^ swz));
      f32x4 zz = {0.f, 0.f, 0.f, 0.f};
      zz = mfma16(a0, qf0, zz);
      zz = mfma16(a1, qf1, zz);
      sc[c] = zz;
    }
    __builtin_amdgcn_s_setprio(0);

    float vals[4][4];
    if (t == qt) {
      const int k0 = t * 64;
#pragma unroll
      for (int c = 0; c < 4; ++c)
#pragma unroll
        for (int r = 0; r < 4; ++r) {
          const int kk = k0 + 16 * c + 4 * g + r;
          vals[c][r] = (kk <= qg) ? sc[c][r] : -INFINITY;
        }
    } else {
#pragma unroll
      for (int c = 0; c < 4; ++c)
#pragma unroll
        for (int r = 0; r < 4; ++r) vals[c][r] = sc[c][r];
    }

    float pm = vals[0][0];
#pragma unroll
    for (int c = 0; c < 4; ++c)
#pragma unroll
      for (int r = 0; r < 4; ++r) pm = fmaxf(pm, vals[c][r]);
    pm = fmaxf(pm, __shfl_xor(pm, 16));
    pm = fmaxf(pm, __shfl_xor(pm, 32));

    float psum = 0.0f;
    if (__any(pm - m > 8.0f)) {
      const float mnew = fmaxf(m, pm);
      const float alpha = __expf(m - mnew);
#pragma unroll
      for (int c = 0; c < 4; ++c)
#pragma unroll
        for (int r = 0; r < 4; ++r) {
          const float pv = __expf(vals[c][r] - mnew);
          vals[c][r] = pv;
          psum += pv;
        }
      psum += __shfl_xor(psum, 16);
      psum += __shfl_xor(psum, 32);
      l = l * alpha + psum;
      m = mnew;
#pragma unroll
      for (int r = 0; r < 4; ++r) {
        const float ar = __shfl(alpha, 4 * g + r);
#pragma unroll
        for (int ht = 0; ht < 4; ++ht) o[ht][r] *= ar;
      }
    } else {
#pragma unroll
      for (int c = 0; c < 4; ++c)
#pragma unroll
        for (int r = 0; r < 4; ++r) {
          const float pv = __expf(vals[c][r] - m);
          vals[c][r] = pv;
          psum += pv;
        }
      psum += __shfl_xor(psum, 16);
      psum += __shfl_xor(psum, 32);
      l += psum;
    }

#pragma unroll
    for (int c = 0; c < 4; ++c) {
      uint2 pk;
      pk.x = (unsigned)f2bf(vals[c][0]) | ((unsigned)f2bf(vals[c][1]) << 16);
      pk.y = (unsigned)f2bf(vals[c][2]) | ((unsigned)f2bf(vals[c][3]) << 16);
      *(uint2*)(Pw + lq * 128 + ((32 * c + 8 * g) ^ swz)) = pk;
    }

    __builtin_amdgcn_s_setprio(1);
#pragma unroll
    for (int ht = 0; ht < 4; ++ht) {
      const int vb = (16 * ht + lq) << 7;
#pragma unroll
      for (int s = 0; s < 2; ++s) {
        const bf16x8 pf = *(const bf16x8*)(Pw + lq * 128 + ((64 * s + 16 * g) ^ swz));
        const bf16x8 vf = *(const bf16x8*)(Vs + ((vb + (s << 6) + (g << 4)) ^ swz));
        o[ht] = mfma16(pf, vf, o[ht]);
      }
    }
    __builtin_amdgcn_s_setprio(0);

    __syncthreads();
  }

  const int b = bh >> 4;
  const int h = bh & 15;
#pragma unroll
  for (int r = 0; r < 4; ++r) {
    const float linv = 1.0f / __shfl(l, 4 * g + r);
    const int srw = q0 + wid * 16 + 4 * g + r;
    const size_t base = ((size_t)(b * NB_S + srw)) * NB_D + h * NB_HD;
#pragma unroll
    for (int ht = 0; ht < 4; ++ht) {
      const float v = o[ht][r] * linv;
      const ushort hv = f2bf(v);
      OH[base + 16 * ht + lq] = hv;
      OL[base + 16 * ht + lq] = f2bf(v - bf2f(hv));
    }
  }
}

extern "C" void kernel_launch(void* const* d_in, const int* in_sizes, int n_in,
                              void* d_out, int out_size, void* d_ws, size_t ws_size,
                              hipStream_t stream) {
  const float* hs = (const float*)d_in[0];
  const float* wq = (const float*)d_in[1];
  const float* wk = (const float*)d_in[2];
  const float* wv = (const float*)d_in[3];
  const float* wo = (const float*)d_in[4];
  float* out = (float*)d_out;

  const size_t E = (size_t)NB_B * NB_S * NB_D;  // 4194304
  char* w = (char*)d_ws;
  ushort* WhiA = (ushort*)w;
  ushort* WloA = WhiA + ((size_t)4 << 20);
  ushort* Ahi = WloA + ((size_t)4 << 20);
  ushort* Alo = Ahi + E;
  ushort* Qd = Alo + E;
  ushort* Kd = Qd + E;
  ushort* Vt = Kd + E;
  float* tab = (float*)(Vt + E);

  k_rope_table<<<dim3(128), 256, 0, stream>>>(tab);
  k_split<<<dim3(2048), 256, 0, stream>>>(hs, Ahi, Alo);
  k_splitw<<<dim3(512, 1, 4), 256, 0, stream>>>(wq, wk, wv, wo, WhiA, WloA);

  // merged Q,K,V projection: one 768-block dispatch
  k_gemm_mfma<3><<<dim3(768), 256, 0, stream>>>(
      Ahi, Alo, WhiA, WloA, (void*)Qd, (void*)Kd, (void*)Vt, tab, 0);

  // attention writes split hi/lo into Ahi/Alo (dead after projections)
  k_attn<<<dim3(32, 32), 256, 0, stream>>>(Qd, Kd, Vt, Ahi, Alo);

  // output projection
  k_gemm_mfma<1><<<dim3(256), 256, 0, stream>>>(
      Ahi, Alo, WhiA + ((size_t)3 << 20), WloA + ((size_t)3 << 20),
      (void*)out, (void*)out, (void*)out, tab, 3);
}